// Round 22
// baseline (381.677 us; speedup 1.0000x reference)
//
#include <hip/hip_runtime.h>

typedef __bf16 bf16_t;
typedef __attribute__((ext_vector_type(8))) __bf16 bf16x8;
typedef __attribute__((ext_vector_type(4))) __bf16 bf16x4;
typedef __attribute__((ext_vector_type(4))) float f32x4;

#define B_  4
#define L_  2048
#define D_  1024
#define M_  (B_*L_)
#define N3_ (3*D_)

__device__ __forceinline__ void gload_lds16(const void* g, void* l) {
  __builtin_amdgcn_global_load_lds(
      (__attribute__((address_space(1))) void*)(g),
      (__attribute__((address_space(3))) void*)(l), 16, 0, 0);
}

// Stage one 128-row x 32-col bf16 K-tile (8 KiB) into LDS with 256 threads
// (2 gloads/thread -> vmcnt +2 per wave). LDS dest linear granules; global
// source chunk pre-swizzled (chunk ^= (row>>1)&3) so ds_reads are ~2-way
// bank-aliased (free). Granule t: row t>>2, chunk t&3; csrc involution.
__device__ __forceinline__ void stage32(const bf16_t* __restrict__ g, int ld, int grow0,
                                        int k0, bf16_t* lds_tile, int tid) {
  const int csrc = (((tid & 3) ^ ((tid >> 3) & 3)) << 3);
  const int row = tid >> 2;                      // 0..63
  bf16_t* l0 = lds_tile + ((tid >> 6) << 9);     // wave-uniform base (512 elems/wave)
  const bf16_t* g0 = g + (size_t)(grow0 + row) * ld + (k0 + csrc);
  gload_lds16(g0, l0);
  gload_lds16(g0 + (size_t)64 * ld, l0 + 2048);  // rows 64..127
}

// BK=32 K-tile: 2 phases, 1 barrier each, counted-gate register read-ahead.
// A 3-buf, B 2-buf (40 KiB total -> 4 blocks/CU).
//  P0: read aHi(j)[2]; stage A(j+2)[2]; lgkm(2) gates P1(j-1)'s 6 reads;
//      8 MFMA (aLo x b); vmcnt(2) retires A(j+1),B(j+1), leaves A(j+2); barrier.
//  P1: read aLo(j+1)[2]+b(j+1)[4]; stage B(j+2)[2]; lgkm(6) gates aHi;
//      8 MFMA (aHi x b); barrier.
#define KTILE32(J, AC, AN1, AN2, BCr, BNx, bC, bN)                                \
  do {                                                                            \
    const int j_ = (J);                                                           \
    aM1_[0] = *(const bf16x8*)(AC + abase + 2 * 512 + co);                        \
    aM1_[1] = *(const bf16x8*)(AC + abase + 3 * 512 + co);                        \
    if (j_ + 2 < NT) stage32(A, lda, r0, (j_ + 2) * 32, AN2, tid);                \
    asm volatile("s_waitcnt lgkmcnt(2)" ::: "memory");                            \
    __builtin_amdgcn_sched_barrier(0);                                            \
    __builtin_amdgcn_s_setprio(1);                                                \
    _Pragma("unroll")                                                             \
    for (int mi = 0; mi < 2; ++mi)                                                \
      _Pragma("unroll")                                                           \
      for (int ni = 0; ni < 4; ++ni)                                              \
        acc[mi][ni] = __builtin_amdgcn_mfma_f32_16x16x32_bf16(                    \
            bC[ni], aM0_[mi], acc[mi][ni], 0, 0, 0);                              \
    __builtin_amdgcn_s_setprio(0);                                                \
    if (j_ + 2 < NT) asm volatile("s_waitcnt vmcnt(2)" ::: "memory");             \
    else             asm volatile("s_waitcnt vmcnt(0)" ::: "memory");             \
    asm volatile("s_barrier" ::: "memory");                                       \
    if (j_ + 1 < NT) {                                                            \
      aM0_[0] = *(const bf16x8*)(AN1 + abase + co);                               \
      aM0_[1] = *(const bf16x8*)(AN1 + abase + 512 + co);                         \
      _Pragma("unroll")                                                           \
      for (int ni = 0; ni < 4; ++ni)                                              \
        bN[ni] = *(const bf16x8*)(BNx + bbase + ni * 512 + co);                   \
      if (j_ + 2 < NT) stage32(Bt, ldb, c0, (j_ + 2) * 32, BCr, tid);             \
      asm volatile("s_waitcnt lgkmcnt(6)" ::: "memory");                          \
    } else {                                                                      \
      asm volatile("s_waitcnt lgkmcnt(0)" ::: "memory");                          \
    }                                                                             \
    __builtin_amdgcn_sched_barrier(0);                                            \
    __builtin_amdgcn_s_setprio(1);                                                \
    _Pragma("unroll")                                                             \
    for (int mi = 0; mi < 2; ++mi)                                                \
      _Pragma("unroll")                                                           \
      for (int ni = 0; ni < 4; ++ni)                                              \
        acc[2 + mi][ni] = __builtin_amdgcn_mfma_f32_16x16x32_bf16(                \
            bC[ni], aM1_[mi], acc[2 + mi][ni], 0, 0, 0);                          \
    __builtin_amdgcn_s_setprio(0);                                                \
    asm volatile("s_barrier" ::: "memory");                                       \
  } while (0)

// C[M][N] = A[M][K] * Bt[N][K]^T (+bias). 128x128 tile, BK=32, 256 threads
// (4 waves 2M x 2N, wave out 64x64). A 3-buf + B 2-buf = 40 KiB LDS ->
// 4 blocks/CU co-residency. XCD swizzle (T1).
template<bool OUT_BF16, bool CAUSAL, bool VARK, bool PROJ>
__global__ __launch_bounds__(256, 4)
void gemm4(const bf16_t* __restrict__ A, int lda, long sA,
           const bf16_t* __restrict__ Bt, int ldb, long sB,
           void* __restrict__ Cv, int ldc, long sC,
           const float* __restrict__ b0, const float* __restrict__ b1,
           const float* __restrict__ b2, int K)
{
  const int gx = gridDim.x;
  const int nwg = gx * gridDim.y;
  const int orig = blockIdx.y * gx + blockIdx.x;
  const int swz = (orig & 7) * (nwg >> 3) + (orig >> 3);   // bijective: nwg % 8 == 0
  const int bx = swz % gx, by = swz / gx;
  if (CAUSAL && bx > by) return;   // 128x128 tiles: fully above diagonal

  const int z = blockIdx.z;
  A  += (size_t)z * sA;
  Bt += (size_t)z * sB;

  const int r0 = by * 128, c0 = bx * 128;
  const int kend = VARK ? min(K, r0 + 128) : K;
  const int NT = kend >> 5;   // always even (VARK: 4(by+1))

  extern __shared__ __align__(16) bf16_t smem[];
  bf16_t* Ab0 = smem;                 // 3 x [128*32] A rotating bufs (24 KiB)
  bf16_t* Ab1 = smem + 4096;
  bf16_t* Ab2 = smem + 8192;
  bf16_t* Bb0 = smem + 12288;         // 2 x [128*32] B bufs (16 KiB)
  bf16_t* Bb1 = smem + 16384;

  const int tid = threadIdx.x;
  const int wid = tid >> 6, lane = tid & 63;
  const int wm = wid >> 1, wn = wid & 1;              // 2M x 2N waves
  const int rl = lane & 15, cg = lane >> 4;
  const int co = ((cg ^ ((rl >> 1) & 3)) << 3);       // swizzled chunk (BK=32)
  const int abase = (wm * 64 + rl) * 32;              // + mi*512 (mi<4)
  const int bbase = (wn * 64 + rl) * 32;              // + ni*512 (ni<4)

  f32x4 acc[4][4] = {};
  bf16x8 aM0_[2], aM1_[2];
  bf16x8 bA_[4], bB_[4];

  // prologue: stage A(0),B(0),A(1),B(1); vmcnt(4) drains A0,B0 (leaves A1,B1);
  // barrier; pre-read aLo(0)[2] + b(0)[4] (gated by KTILE(0)'s lgkm(2)).
  stage32(A,  lda, r0, 0,  Ab0, tid);
  stage32(Bt, ldb, c0, 0,  Bb0, tid);
  stage32(A,  lda, r0, 32, Ab1, tid);
  stage32(Bt, ldb, c0, 32, Bb1, tid);
  asm volatile("s_waitcnt vmcnt(4)" ::: "memory");
  asm volatile("s_barrier" ::: "memory");
  aM0_[0] = *(const bf16x8*)(Ab0 + abase + co);
  aM0_[1] = *(const bf16x8*)(Ab0 + abase + 512 + co);
  #pragma unroll
  for (int ni = 0; ni < 4; ++ni)
    bA_[ni] = *(const bf16x8*)(Bb0 + bbase + ni * 512 + co);

  bf16_t *A0 = Ab0, *A1 = Ab1, *A2 = Ab2;
  for (int j = 0; j < NT; j += 2) {
    KTILE32(j,     A0, A1, A2, Bb0, Bb1, bA_, bB_);
    KTILE32(j + 1, A1, A2, A0, Bb1, Bb0, bB_, bA_);
    bf16_t* t = A2; A2 = A1; A1 = A0; A0 = t;
  }

  // epilogue: swapped-operand layout -> lane holds 4 consecutive N-cols at
  // c = c0 + wn*64 + ni*16 + (lane>>4)*4, row r = r0 + wm*64 + mi*16 + (lane&15)
  const int ml = lane & 15, ng = cg * 4;
  #pragma unroll
  for (int mi = 0; mi < 4; ++mi) {
    const int r = r0 + wm * 64 + mi * 16 + ml;
    #pragma unroll
    for (int ni = 0; ni < 4; ++ni) {
      const int c = c0 + wn * 64 + ni * 16 + ng;
      f32x4 v = acc[mi][ni];
      if (PROJ) {
        const float* bias = (c < D_) ? b0 : (c < 2 * D_) ? b1 : b2;
        const float4 bb = *(const float4*)(bias + (c & (D_ - 1)));
        const float sc = (c < D_) ? 0.03125f : 1.0f;   // q pre-scaled by 1/sqrt(D)
        v[0] = (v[0] + bb.x) * sc; v[1] = (v[1] + bb.y) * sc;
        v[2] = (v[2] + bb.z) * sc; v[3] = (v[3] + bb.w) * sc;
      }
      if (OUT_BF16) {
        bf16x4 o = {(bf16_t)v[0], (bf16_t)v[1], (bf16_t)v[2], (bf16_t)v[3]};
        *(bf16x4*)((bf16_t*)Cv + (size_t)z * sC + (size_t)r * ldc + c) = o;
      } else {
        *(f32x4*)((float*)Cv + (size_t)z * sC + (size_t)r * ldc + c) = v;
      }
    }
  }
}

__device__ __forceinline__ float blk_red_max(float v, float* red, int lane, int wid) {
  #pragma unroll
  for (int o = 32; o; o >>= 1) v = fmaxf(v, __shfl_down(v, o));
  __syncthreads();
  if (lane == 0) red[wid] = v;
  __syncthreads();
  return fmaxf(fmaxf(red[0], red[1]), fmaxf(red[2], red[3]));
}
__device__ __forceinline__ float blk_red_sum(float v, float* red, int lane, int wid) {
  #pragma unroll
  for (int o = 32; o; o >>= 1) v += __shfl_down(v, o);
  __syncthreads();
  if (lane == 0) red[wid] = v;
  __syncthreads();
  return red[0] + red[1] + red[2] + red[3];
}

// block (x=row r, y=batch); softmax over bf16 S[r][0..r], vectorized bf16x8:
// thread t owns cols [8t, 8t+8). Write bf16 P zero-filled to 256-aligned end.
__global__ __launch_bounds__(256)
void softmax_causal(const bf16_t* __restrict__ S, bf16_t* __restrict__ P) {
  const int r = blockIdx.x;
  const int n = r + 1;
  const int kend = min(((n + 255) >> 8) << 8, L_);
  const bf16_t* row = S + (size_t)blockIdx.y * L_ * L_ + (size_t)r * L_;
  bf16_t* prow = P + (size_t)blockIdx.y * L_ * L_ + (size_t)r * L_;
  const int tid = threadIdx.x, lane = tid & 63, wid = tid >> 6;
  const int c0 = tid * 8;
  __shared__ float red[4];

  const bf16x8 v8 = *(const bf16x8*)(row + c0);   // garbage beyond n is masked below
  float s[8];
  #pragma unroll
  for (int i = 0; i < 8; ++i)
    s[i] = (c0 + i < n) ? (float)v8[i] : -3.402823466e38f;

  float mx = s[0];
  #pragma unroll
  for (int i = 1; i < 8; ++i) mx = fmaxf(mx, s[i]);
  mx = blk_red_max(mx, red, lane, wid);

  float e[8]; float sum = 0.f;
  #pragma unroll
  for (int i = 0; i < 8; ++i) {
    const float v = (c0 + i < n) ? __expf(s[i] - mx) : 0.f;
    e[i] = v; sum += v;
  }
  sum = blk_red_sum(sum, red, lane, wid);
  const float inv = 1.0f / sum;

  if (c0 < kend) {
    bf16x8 o;
    #pragma unroll
    for (int i = 0; i < 8; ++i) o[i] = (bf16_t)(e[i] * inv);
    *(bf16x8*)(prow + c0) = o;     // e==0 beyond n -> zeros
  }
}

__global__ void cvt_f32_bf16(const float* __restrict__ in, bf16_t* __restrict__ out, int n4) {
  const int stride = gridDim.x * blockDim.x;
  for (int i = blockIdx.x * blockDim.x + threadIdx.x; i < n4; i += stride) {
    const float4 v = ((const float4*)in)[i];
    bf16x4 o = { (bf16_t)v.x, (bf16_t)v.y, (bf16_t)v.z, (bf16_t)v.w };
    ((bf16x4*)out)[i] = o;
  }
}

// oT[z][n][k] = w_z[k][n], fp32 -> bf16, 1024x1024 each; z concatenated -> [3072][1024]
__global__ void transpose_w3(const float* __restrict__ w0, const float* __restrict__ w1,
                             const float* __restrict__ w2, bf16_t* __restrict__ oT) {
  const float* w = blockIdx.z == 0 ? w0 : (blockIdx.z == 1 ? w1 : w2);
  bf16_t* o = oT + (size_t)blockIdx.z * D_ * D_;
  __shared__ float t[32][33];
  const int tx = threadIdx.x, ty = threadIdx.y;
  const int x  = blockIdx.x * 32 + tx;
  const int y0 = blockIdx.y * 32;
  #pragma unroll
  for (int j = 0; j < 4; ++j)
    t[ty + j * 8][tx] = w[(size_t)(y0 + ty + j * 8) * D_ + x];
  __syncthreads();
  const int x2 = y0 + tx;
  const int y2 = blockIdx.x * 32;
  #pragma unroll
  for (int j = 0; j < 4; ++j)
    o[(size_t)(y2 + ty + j * 8) * D_ + x2] = (bf16_t)t[tx][ty + j * 8];
}

// out[C][R] = in[r][coff + c] for r<R, c<C; in has leading dim ld_in (bf16)
__global__ void transpose_bf16(const bf16_t* __restrict__ in, int ld_in, int coff,
                               bf16_t* __restrict__ out, int R, int C) {
  __shared__ bf16_t t[32][34];
  const int tx = threadIdx.x, ty = threadIdx.y;
  const int x  = blockIdx.x * 32 + tx;
  const int y0 = blockIdx.y * 32;
  #pragma unroll
  for (int j = 0; j < 4; ++j)
    t[ty + j * 8][tx] = in[(size_t)(y0 + ty + j * 8) * ld_in + coff + x];
  __syncthreads();
  const int x2 = y0 + tx;
  const int y2 = blockIdx.x * 32;
  #pragma unroll
  for (int j = 0; j < 4; ++j)
    out[(size_t)(y2 + ty + j * 8) * R + x2] = t[tx][ty + j * 8];
}

extern "C" void kernel_launch(void* const* d_in, const int* in_sizes, int n_in,
                              void* d_out, int out_size, void* d_ws, size_t ws_size,
                              hipStream_t stream) {
  const float* x  = (const float*)d_in[0];
  // d_in[1] = causal mask, structurally known -> ignored
  const float* wq = (const float*)d_in[2];
  const float* bq = (const float*)d_in[3];
  const float* wk = (const float*)d_in[4];
  const float* bk = (const float*)d_in[5];
  const float* wv = (const float*)d_in[6];
  const float* bv = (const float*)d_in[7];
  float* out = (float*)d_out;

  // workspace layout (bf16 elems), ~118 MB total
  bf16_t* xb   = (bf16_t*)d_ws;                    // [8192][1024]    16 MB
  bf16_t* wT   = xb  + (size_t)M_ * D_;            // [3072][1024]     6 MB (W^T, q|k|v)
  bf16_t* qkv  = wT  + (size_t)N3_ * D_;           // [8192][3072]    48 MB (q pre-scaled)
  bf16_t* vbT  = qkv + (size_t)M_ * N3_;           // [1024][8192]    16 MB (V^T)
  bf16_t* Sb   = vbT + (size_t)M_ * D_;            // [4][2048][2048] 32 MB bf16
  bf16_t* Pfull = qkv;                             // [4][2048][2048] 32 MB (aliases dead qkv)

  const size_t SMEM = 40960;   // 40 KiB: A 3-buf (24K) + B 2-buf (16K) -> 4 blocks/CU

  cvt_f32_bf16<<<1024, 256, 0, stream>>>(x, xb, M_ * D_ / 4);
  transpose_w3<<<dim3(32, 32, 3), dim3(32, 8), 0, stream>>>(wq, wk, wv, wT);

  // fused projection GEMM: C[8192][3072] = xb @ wT^T, bias/scale per column
  gemm4<true, false, false, true><<<dim3(N3_ / 128, M_ / 128), 256, SMEM, stream>>>(
      xb, D_, 0, wT, D_, 0, qkv, N3_, 0, bq, bk, bv, D_);

  // V^T from qkv columns [2048,3072)
  transpose_bf16<<<dim3(D_ / 32, M_ / 32), dim3(32, 8), 0, stream>>>(qkv, N3_, 2 * D_, vbT, M_, D_);

  // QK^T for all batches (Q = cols [0,1024), K = cols [1024,2048)), bf16 logits
  gemm4<true, true, false, false><<<dim3(L_ / 128, L_ / 128, B_), 256, SMEM, stream>>>(
      qkv, N3_, (long)L_ * N3_, qkv + D_, N3_, (long)L_ * N3_, Sb, L_, (long)L_ * L_,
      nullptr, nullptr, nullptr, D_);

  // softmax for all batches (writes Pfull over dead qkv)
  softmax_causal<<<dim3(L_, B_), 256, 0, stream>>>(Sb, Pfull);

  // PV for all batches
  gemm4<false, false, true, false><<<dim3(D_ / 128, L_ / 128, B_), 256, SMEM, stream>>>(
      Pfull, L_, (long)L_ * L_, vbT, M_, (long)L_, out, D_, (long)L_ * D_,
      nullptr, nullptr, nullptr, L_);
}

// Round 23
// 168.217 us; speedup vs baseline: 2.2690x; 2.2690x over previous
//
#include <hip/hip_runtime.h>

typedef __bf16 bf16_t;
typedef __attribute__((ext_vector_type(8))) __bf16 bf16x8;
typedef __attribute__((ext_vector_type(4))) __bf16 bf16x4;
typedef __attribute__((ext_vector_type(4))) float f32x4;

#define B_  4
#define L_  2048
#define D_  1024
#define M_  (B_*L_)
#define N3_ (3*D_)

__device__ __forceinline__ void gload_lds16(const void* g, void* l) {
  __builtin_amdgcn_global_load_lds(
      (__attribute__((address_space(1))) void*)(g),
      (__attribute__((address_space(3))) void*)(l), 16, 0, 0);
}

// Stage one full 128-row x 64-col bf16 K-tile into LDS with 256 threads
// (4 gloads/thread -> vmcnt +4). LDS dest linear; global source column
// pre-swizzled (chunk ^= row&7) so swizzled ds_reads are conflict-free (T2).
__device__ __forceinline__ void stage_tile4(const bf16_t* __restrict__ g, int ld, int grow0,
                                            int k0, bf16_t* lds_tile, int tid) {
  const int lane = tid & 63;
  const int csrc = ((lane & 7) ^ (lane >> 3)) << 3;
  const int rsub = tid >> 3;                         // 0..31
  bf16_t* l0 = lds_tile + (size_t)((tid >> 6) << 3) * 64;
  const bf16_t* g0 = g + (size_t)(grow0 + rsub) * ld + (k0 + csrc);
  gload_lds16(g0, l0);
  gload_lds16(g0 + (size_t)32 * ld, l0 + 32 * 64);
  gload_lds16(g0 + (size_t)64 * ld, l0 + 64 * 64);
  gload_lds16(g0 + (size_t)96 * ld, l0 + 96 * 64);
}

// K-tile, r9-geometry at 4 waves: 2 phases, 1 barrier each, register
// read-ahead with counted lgkm gates; A 3-buf, B 2-buf.
//  P0: read aHi(j)[4]; stage A(j+2)[4 gloads]; lgkm(4) gates P1(j-1)'s batch;
//      16 MFMA (aLo x b); vmcnt(4) retires A(j+1),B(j+1); barrier.
//  P1: read aLo(j+1)[4]+b(j+1)[8]; stage B(j+2)[4]; lgkm(12) gates aHi;
//      16 MFMA (aHi x b); barrier.
#define KTILE4(J, AC, AN1, AN2, BCr, BNx, bC, bN)                                 \
  do {                                                                            \
    const int j_ = (J);                                                           \
    _Pragma("unroll")                                                             \
    for (int mi = 0; mi < 2; ++mi) {                                              \
      aM1_[mi][0] = *(const bf16x8*)(AC + abase + (2 + mi) * 1024 + co0);         \
      aM1_[mi][1] = *(const bf16x8*)(AC + abase + (2 + mi) * 1024 + co1);         \
    }                                                                             \
    if (j_ + 2 < NT) stage_tile4(A, lda, r0, (j_ + 2) * 64, AN2, tid);            \
    asm volatile("s_waitcnt lgkmcnt(4)" ::: "memory");                            \
    __builtin_amdgcn_sched_barrier(0);                                            \
    __builtin_amdgcn_s_setprio(1);                                                \
    _Pragma("unroll")                                                             \
    for (int mi = 0; mi < 2; ++mi)                                                \
      _Pragma("unroll")                                                           \
      for (int ni = 0; ni < 4; ++ni) {                                            \
        acc[mi][ni] = __builtin_amdgcn_mfma_f32_16x16x32_bf16(                    \
            bC[ni][0], aM0_[mi][0], acc[mi][ni], 0, 0, 0);                        \
        acc[mi][ni] = __builtin_amdgcn_mfma_f32_16x16x32_bf16(                    \
            bC[ni][1], aM0_[mi][1], acc[mi][ni], 0, 0, 0);                        \
      }                                                                           \
    __builtin_amdgcn_s_setprio(0);                                                \
    if (j_ + 2 < NT) asm volatile("s_waitcnt vmcnt(4)" ::: "memory");             \
    else             asm volatile("s_waitcnt vmcnt(0)" ::: "memory");             \
    asm volatile("s_barrier" ::: "memory");                                       \
    if (j_ + 1 < NT) {                                                            \
      _Pragma("unroll")                                                           \
      for (int mi = 0; mi < 2; ++mi) {                                            \
        aM0_[mi][0] = *(const bf16x8*)(AN1 + abase + mi * 1024 + co0);            \
        aM0_[mi][1] = *(const bf16x8*)(AN1 + abase + mi * 1024 + co1);            \
      }                                                                           \
      _Pragma("unroll")                                                           \
      for (int ni = 0; ni < 4; ++ni) {                                            \
        bN[ni][0] = *(const bf16x8*)(BNx + bbase + ni * 1024 + co0);              \
        bN[ni][1] = *(const bf16x8*)(BNx + bbase + ni * 1024 + co1);              \
      }                                                                           \
      if (j_ + 2 < NT) stage_tile4(Bt, ldb, c0, (j_ + 2) * 64, BCr, tid);         \
      asm volatile("s_waitcnt lgkmcnt(12)" ::: "memory");                         \
    } else {                                                                      \
      asm volatile("s_waitcnt lgkmcnt(0)" ::: "memory");                          \
    }                                                                             \
    __builtin_amdgcn_sched_barrier(0);                                            \
    __builtin_amdgcn_s_setprio(1);                                                \
    _Pragma("unroll")                                                             \
    for (int mi = 0; mi < 2; ++mi)                                                \
      _Pragma("unroll")                                                           \
      for (int ni = 0; ni < 4; ++ni) {                                            \
        acc[2 + mi][ni] = __builtin_amdgcn_mfma_f32_16x16x32_bf16(                \
            bC[ni][0], aM1_[mi][0], acc[2 + mi][ni], 0, 0, 0);                    \
        acc[2 + mi][ni] = __builtin_amdgcn_mfma_f32_16x16x32_bf16(                \
            bC[ni][1], aM1_[mi][1], acc[2 + mi][ni], 0, 0, 0);                    \
      }                                                                           \
    __builtin_amdgcn_s_setprio(0);                                                \
    asm volatile("s_barrier" ::: "memory");                                       \
  } while (0)

// C[M][N] = A[M][K] * Bt[N][K]^T (+bias). 128x128 tile, BK=64, 256 threads
// (4 waves 2M x 2N, wave out 64x64). r7/r9 pipeline at 80 KiB LDS ->
// 2 blocks/CU co-residency (m114 cross-block overlap). XCD swizzle (T1).
template<bool OUT_BF16, bool CAUSAL, bool VARK, bool PROJ>
__global__ __launch_bounds__(256, 2)
void gemm4(const bf16_t* __restrict__ A, int lda, long sA,
           const bf16_t* __restrict__ Bt, int ldb, long sB,
           void* __restrict__ Cv, int ldc, long sC,
           const float* __restrict__ b0, const float* __restrict__ b1,
           const float* __restrict__ b2, int K)
{
  const int gx = gridDim.x;
  const int nwg = gx * gridDim.y;
  const int orig = blockIdx.y * gx + blockIdx.x;
  const int swz = (orig & 7) * (nwg >> 3) + (orig >> 3);   // bijective: nwg % 8 == 0
  const int bx = swz % gx, by = swz / gx;
  if (CAUSAL && bx > by) return;   // 128x128 tiles: fully above diagonal

  const int z = blockIdx.z;
  A  += (size_t)z * sA;
  Bt += (size_t)z * sB;

  const int r0 = by * 128, c0 = bx * 128;
  const int kend = VARK ? min(K, r0 + 128) : K;
  const int NT = kend >> 6;   // always even (VARK: 2(by+1))

  extern __shared__ __align__(16) bf16_t smem[];
  bf16_t* Ab0 = smem;                 // 3 x [128*64] A rotating bufs (48 KiB)
  bf16_t* Ab1 = smem + 8192;
  bf16_t* Ab2 = smem + 16384;
  bf16_t* Bb0 = smem + 24576;         // 2 x [128*64] B bufs (32 KiB)
  bf16_t* Bb1 = smem + 32768;

  const int tid = threadIdx.x;
  const int wid = tid >> 6, lane = tid & 63;
  const int wm = wid >> 1, wn = wid & 1;              // 2M x 2N waves
  const int rl = lane & 15, cg = lane >> 4, x0 = lane & 7;
  const int co0 = ((cg ^ x0) << 3);                   // swizzled k-chunk, ks=0
  const int co1 = (((4 + cg) ^ x0) << 3);             // ks=1
  const int abase = (wm * 64 + rl) * 64;              // + mi*1024 (mi<4)
  const int bbase = (wn * 64 + rl) * 64;              // + ni*1024 (ni<4)

  f32x4 acc[4][4] = {};
  bf16x8 aM0_[2][2], aM1_[2][2];
  bf16x8 bA_[4][2], bB_[4][2];

  // prologue: stage A(0),B(0),A(1),B(1); drain A0,B0 (vmcnt(8) leaves A1,B1);
  // pre-read aLo(0) + b(0) (12 ds_reads, gated by KTILE(0)'s lgkm(4))
  stage_tile4(A,  lda, r0, 0,  Ab0, tid);
  stage_tile4(Bt, ldb, c0, 0,  Bb0, tid);
  stage_tile4(A,  lda, r0, 64, Ab1, tid);
  stage_tile4(Bt, ldb, c0, 64, Bb1, tid);
  asm volatile("s_waitcnt vmcnt(8)" ::: "memory");
  asm volatile("s_barrier" ::: "memory");
  #pragma unroll
  for (int mi = 0; mi < 2; ++mi) {
    aM0_[mi][0] = *(const bf16x8*)(Ab0 + abase + mi * 1024 + co0);
    aM0_[mi][1] = *(const bf16x8*)(Ab0 + abase + mi * 1024 + co1);
  }
  #pragma unroll
  for (int ni = 0; ni < 4; ++ni) {
    bA_[ni][0] = *(const bf16x8*)(Bb0 + bbase + ni * 1024 + co0);
    bA_[ni][1] = *(const bf16x8*)(Bb0 + bbase + ni * 1024 + co1);
  }

  bf16_t *A0 = Ab0, *A1 = Ab1, *A2 = Ab2;
  for (int j = 0; j < NT; j += 2) {
    KTILE4(j,     A0, A1, A2, Bb0, Bb1, bA_, bB_);
    KTILE4(j + 1, A1, A2, A0, Bb1, Bb0, bB_, bA_);
    bf16_t* t = A2; A2 = A1; A1 = A0; A0 = t;
  }

  // epilogue: swapped-operand layout -> lane holds 4 consecutive N-cols at
  // c = c0 + wn*64 + ni*16 + (lane>>4)*4, row r = r0 + wm*64 + mi*16 + (lane&15)
  const int ml = lane & 15, ng = cg * 4;
  #pragma unroll
  for (int mi = 0; mi < 4; ++mi) {
    const int r = r0 + wm * 64 + mi * 16 + ml;
    #pragma unroll
    for (int ni = 0; ni < 4; ++ni) {
      const int c = c0 + wn * 64 + ni * 16 + ng;
      f32x4 v = acc[mi][ni];
      if (PROJ) {
        const float* bias = (c < D_) ? b0 : (c < 2 * D_) ? b1 : b2;
        const float4 bb = *(const float4*)(bias + (c & (D_ - 1)));
        const float sc = (c < D_) ? 0.03125f : 1.0f;   // q pre-scaled by 1/sqrt(D)
        v[0] = (v[0] + bb.x) * sc; v[1] = (v[1] + bb.y) * sc;
        v[2] = (v[2] + bb.z) * sc; v[3] = (v[3] + bb.w) * sc;
      }
      if (OUT_BF16) {
        bf16x4 o = {(bf16_t)v[0], (bf16_t)v[1], (bf16_t)v[2], (bf16_t)v[3]};
        *(bf16x4*)((bf16_t*)Cv + (size_t)z * sC + (size_t)r * ldc + c) = o;
      } else {
        *(f32x4*)((float*)Cv + (size_t)z * sC + (size_t)r * ldc + c) = v;
      }
    }
  }
}

__device__ __forceinline__ float blk_red_max(float v, float* red, int lane, int wid) {
  #pragma unroll
  for (int o = 32; o; o >>= 1) v = fmaxf(v, __shfl_down(v, o));
  __syncthreads();
  if (lane == 0) red[wid] = v;
  __syncthreads();
  return fmaxf(fmaxf(red[0], red[1]), fmaxf(red[2], red[3]));
}
__device__ __forceinline__ float blk_red_sum(float v, float* red, int lane, int wid) {
  #pragma unroll
  for (int o = 32; o; o >>= 1) v += __shfl_down(v, o);
  __syncthreads();
  if (lane == 0) red[wid] = v;
  __syncthreads();
  return red[0] + red[1] + red[2] + red[3];
}

// block (x=row r, y=batch); softmax over bf16 S[r][0..r], vectorized bf16x8:
// thread t owns cols [8t, 8t+8). Write bf16 P zero-filled to 256-aligned end.
__global__ __launch_bounds__(256)
void softmax_causal(const bf16_t* __restrict__ S, bf16_t* __restrict__ P) {
  const int r = blockIdx.x;
  const int n = r + 1;
  const int kend = min(((n + 255) >> 8) << 8, L_);
  const bf16_t* row = S + (size_t)blockIdx.y * L_ * L_ + (size_t)r * L_;
  bf16_t* prow = P + (size_t)blockIdx.y * L_ * L_ + (size_t)r * L_;
  const int tid = threadIdx.x, lane = tid & 63, wid = tid >> 6;
  const int c0 = tid * 8;
  __shared__ float red[4];

  const bf16x8 v8 = *(const bf16x8*)(row + c0);   // garbage beyond n is masked below
  float s[8];
  #pragma unroll
  for (int i = 0; i < 8; ++i)
    s[i] = (c0 + i < n) ? (float)v8[i] : -3.402823466e38f;

  float mx = s[0];
  #pragma unroll
  for (int i = 1; i < 8; ++i) mx = fmaxf(mx, s[i]);
  mx = blk_red_max(mx, red, lane, wid);

  float e[8]; float sum = 0.f;
  #pragma unroll
  for (int i = 0; i < 8; ++i) {
    const float v = (c0 + i < n) ? __expf(s[i] - mx) : 0.f;
    e[i] = v; sum += v;
  }
  sum = blk_red_sum(sum, red, lane, wid);
  const float inv = 1.0f / sum;

  if (c0 < kend) {
    bf16x8 o;
    #pragma unroll
    for (int i = 0; i < 8; ++i) o[i] = (bf16_t)(e[i] * inv);
    *(bf16x8*)(prow + c0) = o;     // e==0 beyond n -> zeros
  }
}

__global__ void cvt_f32_bf16(const float* __restrict__ in, bf16_t* __restrict__ out, int n4) {
  const int stride = gridDim.x * blockDim.x;
  for (int i = blockIdx.x * blockDim.x + threadIdx.x; i < n4; i += stride) {
    const float4 v = ((const float4*)in)[i];
    bf16x4 o = { (bf16_t)v.x, (bf16_t)v.y, (bf16_t)v.z, (bf16_t)v.w };
    ((bf16x4*)out)[i] = o;
  }
}

// oT[z][n][k] = w_z[k][n], fp32 -> bf16, 1024x1024 each; z concatenated -> [3072][1024]
__global__ void transpose_w3(const float* __restrict__ w0, const float* __restrict__ w1,
                             const float* __restrict__ w2, bf16_t* __restrict__ oT) {
  const float* w = blockIdx.z == 0 ? w0 : (blockIdx.z == 1 ? w1 : w2);
  bf16_t* o = oT + (size_t)blockIdx.z * D_ * D_;
  __shared__ float t[32][33];
  const int tx = threadIdx.x, ty = threadIdx.y;
  const int x  = blockIdx.x * 32 + tx;
  const int y0 = blockIdx.y * 32;
  #pragma unroll
  for (int j = 0; j < 4; ++j)
    t[ty + j * 8][tx] = w[(size_t)(y0 + ty + j * 8) * D_ + x];
  __syncthreads();
  const int x2 = y0 + tx;
  const int y2 = blockIdx.x * 32;
  #pragma unroll
  for (int j = 0; j < 4; ++j)
    o[(size_t)(y2 + ty + j * 8) * D_ + x2] = (bf16_t)t[tx][ty + j * 8];
}

// out[C][R] = in[r][coff + c] for r<R, c<C; in has leading dim ld_in (bf16)
__global__ void transpose_bf16(const bf16_t* __restrict__ in, int ld_in, int coff,
                               bf16_t* __restrict__ out, int R, int C) {
  __shared__ bf16_t t[32][34];
  const int tx = threadIdx.x, ty = threadIdx.y;
  const int x  = blockIdx.x * 32 + tx;
  const int y0 = blockIdx.y * 32;
  #pragma unroll
  for (int j = 0; j < 4; ++j)
    t[ty + j * 8][tx] = in[(size_t)(y0 + ty + j * 8) * ld_in + coff + x];
  __syncthreads();
  const int x2 = y0 + tx;
  const int y2 = blockIdx.x * 32;
  #pragma unroll
  for (int j = 0; j < 4; ++j)
    out[(size_t)(y2 + ty + j * 8) * R + x2] = t[tx][ty + j * 8];
}

extern "C" void kernel_launch(void* const* d_in, const int* in_sizes, int n_in,
                              void* d_out, int out_size, void* d_ws, size_t ws_size,
                              hipStream_t stream) {
  const float* x  = (const float*)d_in[0];
  // d_in[1] = causal mask, structurally known -> ignored
  const float* wq = (const float*)d_in[2];
  const float* bq = (const float*)d_in[3];
  const float* wk = (const float*)d_in[4];
  const float* bk = (const float*)d_in[5];
  const float* wv = (const float*)d_in[6];
  const float* bv = (const float*)d_in[7];
  float* out = (float*)d_out;

  // workspace layout (bf16 elems), ~118 MB total
  bf16_t* xb   = (bf16_t*)d_ws;                    // [8192][1024]    16 MB
  bf16_t* wT   = xb  + (size_t)M_ * D_;            // [3072][1024]     6 MB (W^T, q|k|v)
  bf16_t* qkv  = wT  + (size_t)N3_ * D_;           // [8192][3072]    48 MB (q pre-scaled)
  bf16_t* vbT  = qkv + (size_t)M_ * N3_;           // [1024][8192]    16 MB (V^T)
  bf16_t* Sb   = vbT + (size_t)M_ * D_;            // [4][2048][2048] 32 MB bf16
  bf16_t* Pfull = qkv;                             // [4][2048][2048] 32 MB (aliases dead qkv)

  const size_t SMEM = 81920;   // 80 KiB: A 3-buf (48K) + B 2-buf (32K) -> 2 blocks/CU

  cvt_f32_bf16<<<1024, 256, 0, stream>>>(x, xb, M_ * D_ / 4);
  transpose_w3<<<dim3(32, 32, 3), dim3(32, 8), 0, stream>>>(wq, wk, wv, wT);

  // fused projection GEMM: C[8192][3072] = xb @ wT^T, bias/scale per column
  gemm4<true, false, false, true><<<dim3(N3_ / 128, M_ / 128), 256, SMEM, stream>>>(
      xb, D_, 0, wT, D_, 0, qkv, N3_, 0, bq, bk, bv, D_);

  // V^T from qkv columns [2048,3072)
  transpose_bf16<<<dim3(D_ / 32, M_ / 32), dim3(32, 8), 0, stream>>>(qkv, N3_, 2 * D_, vbT, M_, D_);

  // QK^T for all batches (Q = cols [0,1024), K = cols [1024,2048)), bf16 logits
  gemm4<true, true, false, false><<<dim3(L_ / 128, L_ / 128, B_), 256, SMEM, stream>>>(
      qkv, N3_, (long)L_ * N3_, qkv + D_, N3_, (long)L_ * N3_, Sb, L_, (long)L_ * L_,
      nullptr, nullptr, nullptr, D_);

  // softmax for all batches (writes Pfull over dead qkv)
  softmax_causal<<<dim3(L_, B_), 256, 0, stream>>>(Sb, Pfull);

  // PV for all batches (512 blocks = exactly 2/CU, single scheduling round)
  gemm4<false, false, true, false><<<dim3(D_ / 128, L_ / 128, B_), 256, SMEM, stream>>>(
      Pfull, L_, (long)L_ * L_, vbT, M_, (long)L_, out, D_, (long)L_ * D_,
      nullptr, nullptr, nullptr, L_);
}

// Round 24
// 158.264 us; speedup vs baseline: 2.4116x; 1.0629x over previous
//
#include <hip/hip_runtime.h>

typedef __bf16 bf16_t;
typedef __attribute__((ext_vector_type(8))) __bf16 bf16x8;
typedef __attribute__((ext_vector_type(4))) __bf16 bf16x4;
typedef __attribute__((ext_vector_type(4))) float f32x4;

#define B_  4
#define L_  2048
#define D_  1024
#define M_  (B_*L_)
#define N3_ (3*D_)

__device__ __forceinline__ void gload_lds16(const void* g, void* l) {
  __builtin_amdgcn_global_load_lds(
      (__attribute__((address_space(1))) void*)(g),
      (__attribute__((address_space(3))) void*)(l), 16, 0, 0);
}

// Stage one full 128-row x 64-col bf16 K-tile into LDS with 256 threads
// (4 gloads/thread -> vmcnt +4). LDS dest linear; global source column
// pre-swizzled (chunk ^= row&7) so swizzled ds_reads are conflict-free (T2).
__device__ __forceinline__ void stage_tile4(const bf16_t* __restrict__ g, int ld, int grow0,
                                            int k0, bf16_t* lds_tile, int tid) {
  const int lane = tid & 63;
  const int csrc = ((lane & 7) ^ (lane >> 3)) << 3;
  const int rsub = tid >> 3;                         // 0..31
  bf16_t* l0 = lds_tile + (size_t)((tid >> 6) << 3) * 64;
  const bf16_t* g0 = g + (size_t)(grow0 + rsub) * ld + (k0 + csrc);
  gload_lds16(g0, l0);
  gload_lds16(g0 + (size_t)32 * ld, l0 + 32 * 64);
  gload_lds16(g0 + (size_t)64 * ld, l0 + 64 * 64);
  gload_lds16(g0 + (size_t)96 * ld, l0 + 96 * 64);
}

// K-tile, 4 waves: 2 phases, 1 barrier each, register read-ahead with counted
// lgkm gates; A 3-buf, B 2-buf. (r19/r21/r23-proven)
#define KTILE4(J, AC, AN1, AN2, BCr, BNx, bC, bN)                                 \
  do {                                                                            \
    const int j_ = (J);                                                           \
    _Pragma("unroll")                                                             \
    for (int mi = 0; mi < 2; ++mi) {                                              \
      aM1_[mi][0] = *(const bf16x8*)(AC + abase + (2 + mi) * 1024 + co0);         \
      aM1_[mi][1] = *(const bf16x8*)(AC + abase + (2 + mi) * 1024 + co1);         \
    }                                                                             \
    if (j_ + 2 < NT) stage_tile4(A, lda, r0, (j_ + 2) * 64, AN2, tid);            \
    asm volatile("s_waitcnt lgkmcnt(4)" ::: "memory");                            \
    __builtin_amdgcn_sched_barrier(0);                                            \
    __builtin_amdgcn_s_setprio(1);                                                \
    _Pragma("unroll")                                                             \
    for (int mi = 0; mi < 2; ++mi)                                                \
      _Pragma("unroll")                                                           \
      for (int ni = 0; ni < 4; ++ni) {                                            \
        acc[mi][ni] = __builtin_amdgcn_mfma_f32_16x16x32_bf16(                    \
            bC[ni][0], aM0_[mi][0], acc[mi][ni], 0, 0, 0);                        \
        acc[mi][ni] = __builtin_amdgcn_mfma_f32_16x16x32_bf16(                    \
            bC[ni][1], aM0_[mi][1], acc[mi][ni], 0, 0, 0);                        \
      }                                                                           \
    __builtin_amdgcn_s_setprio(0);                                                \
    if (j_ + 2 < NT) asm volatile("s_waitcnt vmcnt(4)" ::: "memory");             \
    else             asm volatile("s_waitcnt vmcnt(0)" ::: "memory");             \
    asm volatile("s_barrier" ::: "memory");                                       \
    if (j_ + 1 < NT) {                                                            \
      _Pragma("unroll")                                                           \
      for (int mi = 0; mi < 2; ++mi) {                                            \
        aM0_[mi][0] = *(const bf16x8*)(AN1 + abase + mi * 1024 + co0);            \
        aM0_[mi][1] = *(const bf16x8*)(AN1 + abase + mi * 1024 + co1);            \
      }                                                                           \
      _Pragma("unroll")                                                           \
      for (int ni = 0; ni < 4; ++ni) {                                            \
        bN[ni][0] = *(const bf16x8*)(BNx + bbase + ni * 1024 + co0);              \
        bN[ni][1] = *(const bf16x8*)(BNx + bbase + ni * 1024 + co1);              \
      }                                                                           \
      if (j_ + 2 < NT) stage_tile4(Bt, ldb, c0, (j_ + 2) * 64, BCr, tid);         \
      asm volatile("s_waitcnt lgkmcnt(12)" ::: "memory");                         \
    } else {                                                                      \
      asm volatile("s_waitcnt lgkmcnt(0)" ::: "memory");                          \
    }                                                                             \
    __builtin_amdgcn_sched_barrier(0);                                            \
    __builtin_amdgcn_s_setprio(1);                                                \
    _Pragma("unroll")                                                             \
    for (int mi = 0; mi < 2; ++mi)                                                \
      _Pragma("unroll")                                                           \
      for (int ni = 0; ni < 4; ++ni) {                                            \
        acc[2 + mi][ni] = __builtin_amdgcn_mfma_f32_16x16x32_bf16(                \
            bC[ni][0], aM1_[mi][0], acc[2 + mi][ni], 0, 0, 0);                    \
        acc[2 + mi][ni] = __builtin_amdgcn_mfma_f32_16x16x32_bf16(                \
            bC[ni][1], aM1_[mi][1], acc[2 + mi][ni], 0, 0, 0);                    \
      }                                                                           \
    __builtin_amdgcn_s_setprio(0);                                                \
    asm volatile("s_barrier" ::: "memory");                                       \
  } while (0)

// C[M][N] = A[M][K] * Bt[N][K]^T (+bias). 128x128 tile, BK=64, 256 threads
// (4 waves 2M x 2N, wave out 64x64). 80 KiB LDS -> 2 blocks/CU. XCD swizzle.
// PROJ: V columns (c >= 2048) are written ONLY transposed into vT[c-2048][r]
// (fused V^T; qkv's V region has no other consumer).
template<bool OUT_BF16, bool CAUSAL, bool VARK, bool PROJ>
__global__ __launch_bounds__(256, 2)
void gemm4(const bf16_t* __restrict__ A, int lda, long sA,
           const bf16_t* __restrict__ Bt, int ldb, long sB,
           void* __restrict__ Cv, int ldc, long sC,
           bf16_t* __restrict__ vT,
           const float* __restrict__ b0, const float* __restrict__ b1,
           const float* __restrict__ b2, int K)
{
  const int gx = gridDim.x;
  const int nwg = gx * gridDim.y;
  const int orig = blockIdx.y * gx + blockIdx.x;
  const int swz = (orig & 7) * (nwg >> 3) + (orig >> 3);   // bijective: nwg % 8 == 0
  const int bx = swz % gx, by = swz / gx;
  if (CAUSAL && bx > by) return;   // 128x128 tiles: fully above diagonal

  const int z = blockIdx.z;
  A  += (size_t)z * sA;
  Bt += (size_t)z * sB;

  const int r0 = by * 128, c0 = bx * 128;
  const int kend = VARK ? min(K, r0 + 128) : K;
  const int NT = kend >> 6;   // always even (VARK: 2(by+1))

  extern __shared__ __align__(16) bf16_t smem[];
  bf16_t* Ab0 = smem;                 // 3 x [128*64] A rotating bufs (48 KiB)
  bf16_t* Ab1 = smem + 8192;
  bf16_t* Ab2 = smem + 16384;
  bf16_t* Bb0 = smem + 24576;         // 2 x [128*64] B bufs (32 KiB)
  bf16_t* Bb1 = smem + 32768;

  const int tid = threadIdx.x;
  const int wid = tid >> 6, lane = tid & 63;
  const int wm = wid >> 1, wn = wid & 1;              // 2M x 2N waves
  const int rl = lane & 15, cg = lane >> 4, x0 = lane & 7;
  const int co0 = ((cg ^ x0) << 3);                   // swizzled k-chunk, ks=0
  const int co1 = (((4 + cg) ^ x0) << 3);             // ks=1
  const int abase = (wm * 64 + rl) * 64;              // + mi*1024 (mi<4)
  const int bbase = (wn * 64 + rl) * 64;              // + ni*1024 (ni<4)

  f32x4 acc[4][4] = {};
  bf16x8 aM0_[2][2], aM1_[2][2];
  bf16x8 bA_[4][2], bB_[4][2];

  // prologue: stage A(0),B(0),A(1),B(1); drain A0,B0 (vmcnt(8) leaves A1,B1);
  // pre-read aLo(0) + b(0)
  stage_tile4(A,  lda, r0, 0,  Ab0, tid);
  stage_tile4(Bt, ldb, c0, 0,  Bb0, tid);
  stage_tile4(A,  lda, r0, 64, Ab1, tid);
  stage_tile4(Bt, ldb, c0, 64, Bb1, tid);
  asm volatile("s_waitcnt vmcnt(8)" ::: "memory");
  asm volatile("s_barrier" ::: "memory");
  #pragma unroll
  for (int mi = 0; mi < 2; ++mi) {
    aM0_[mi][0] = *(const bf16x8*)(Ab0 + abase + mi * 1024 + co0);
    aM0_[mi][1] = *(const bf16x8*)(Ab0 + abase + mi * 1024 + co1);
  }
  #pragma unroll
  for (int ni = 0; ni < 4; ++ni) {
    bA_[ni][0] = *(const bf16x8*)(Bb0 + bbase + ni * 1024 + co0);
    bA_[ni][1] = *(const bf16x8*)(Bb0 + bbase + ni * 1024 + co1);
  }

  bf16_t *A0 = Ab0, *A1 = Ab1, *A2 = Ab2;
  for (int j = 0; j < NT; j += 2) {
    KTILE4(j,     A0, A1, A2, Bb0, Bb1, bA_, bB_);
    KTILE4(j + 1, A1, A2, A0, Bb1, Bb0, bB_, bA_);
    bf16_t* t = A2; A2 = A1; A1 = A0; A0 = t;
  }

  // epilogue: swapped-operand layout -> lane holds 4 consecutive N-cols at
  // c = c0 + wn*64 + ni*16 + (lane>>4)*4, row r = r0 + wm*64 + mi*16 + (lane&15)
  const int ml = lane & 15, ng = cg * 4;
  #pragma unroll
  for (int mi = 0; mi < 4; ++mi) {
    const int r = r0 + wm * 64 + mi * 16 + ml;
    #pragma unroll
    for (int ni = 0; ni < 4; ++ni) {
      const int c = c0 + wn * 64 + ni * 16 + ng;
      f32x4 v = acc[mi][ni];
      if (PROJ) {
        const float* bias = (c < D_) ? b0 : (c < 2 * D_) ? b1 : b2;
        const float4 bb = *(const float4*)(bias + (c & (D_ - 1)));
        const float sc = (c < D_) ? 0.03125f : 1.0f;   // q pre-scaled by 1/sqrt(D)
        v[0] = (v[0] + bb.x) * sc; v[1] = (v[1] + bb.y) * sc;
        v[2] = (v[2] + bb.z) * sc; v[3] = (v[3] + bb.w) * sc;
        if (c >= 2 * D_) {
          // fused V^T: write only transposed (lanes 0-15 -> consecutive r)
          bf16_t* vt = vT + (size_t)(c - 2 * D_) * (size_t)M_ + r;
          vt[0] = (bf16_t)v[0];
          vt[(size_t)M_]     = (bf16_t)v[1];
          vt[(size_t)M_ * 2] = (bf16_t)v[2];
          vt[(size_t)M_ * 3] = (bf16_t)v[3];
          continue;
        }
      }
      if (OUT_BF16) {
        bf16x4 o = {(bf16_t)v[0], (bf16_t)v[1], (bf16_t)v[2], (bf16_t)v[3]};
        *(bf16x4*)((bf16_t*)Cv + (size_t)z * sC + (size_t)r * ldc + c) = o;
      } else {
        *(f32x4*)((float*)Cv + (size_t)z * sC + (size_t)r * ldc + c) = v;
      }
    }
  }
}

__device__ __forceinline__ float blk_red_max(float v, float* red, int lane, int wid) {
  #pragma unroll
  for (int o = 32; o; o >>= 1) v = fmaxf(v, __shfl_down(v, o));
  __syncthreads();
  if (lane == 0) red[wid] = v;
  __syncthreads();
  return fmaxf(fmaxf(red[0], red[1]), fmaxf(red[2], red[3]));
}
__device__ __forceinline__ float blk_red_sum(float v, float* red, int lane, int wid) {
  #pragma unroll
  for (int o = 32; o; o >>= 1) v += __shfl_down(v, o);
  __syncthreads();
  if (lane == 0) red[wid] = v;
  __syncthreads();
  return red[0] + red[1] + red[2] + red[3];
}

// block (x=row r, y=batch); softmax over bf16 S[r][0..r], vectorized bf16x8:
// thread t owns cols [8t, 8t+8). Write bf16 P zero-filled to 256-aligned end.
__global__ __launch_bounds__(256)
void softmax_causal(const bf16_t* __restrict__ S, bf16_t* __restrict__ P) {
  const int r = blockIdx.x;
  const int n = r + 1;
  const int kend = min(((n + 255) >> 8) << 8, L_);
  const bf16_t* row = S + (size_t)blockIdx.y * L_ * L_ + (size_t)r * L_;
  bf16_t* prow = P + (size_t)blockIdx.y * L_ * L_ + (size_t)r * L_;
  const int tid = threadIdx.x, lane = tid & 63, wid = tid >> 6;
  const int c0 = tid * 8;
  __shared__ float red[4];

  const bf16x8 v8 = *(const bf16x8*)(row + c0);   // garbage beyond n is masked below
  float s[8];
  #pragma unroll
  for (int i = 0; i < 8; ++i)
    s[i] = (c0 + i < n) ? (float)v8[i] : -3.402823466e38f;

  float mx = s[0];
  #pragma unroll
  for (int i = 1; i < 8; ++i) mx = fmaxf(mx, s[i]);
  mx = blk_red_max(mx, red, lane, wid);

  float e[8]; float sum = 0.f;
  #pragma unroll
  for (int i = 0; i < 8; ++i) {
    const float v = (c0 + i < n) ? __expf(s[i] - mx) : 0.f;
    e[i] = v; sum += v;
  }
  sum = blk_red_sum(sum, red, lane, wid);
  const float inv = 1.0f / sum;

  if (c0 < kend) {
    bf16x8 o;
    #pragma unroll
    for (int i = 0; i < 8; ++i) o[i] = (bf16_t)(e[i] * inv);
    *(bf16x8*)(prow + c0) = o;     // e==0 beyond n -> zeros
  }
}

__global__ void cvt_f32_bf16(const float* __restrict__ in, bf16_t* __restrict__ out, int n4) {
  const int stride = gridDim.x * blockDim.x;
  for (int i = blockIdx.x * blockDim.x + threadIdx.x; i < n4; i += stride) {
    const float4 v = ((const float4*)in)[i];
    bf16x4 o = { (bf16_t)v.x, (bf16_t)v.y, (bf16_t)v.z, (bf16_t)v.w };
    ((bf16x4*)out)[i] = o;
  }
}

// oT[z][n][k] = w_z[k][n], fp32 -> bf16, 1024x1024 each; z concatenated -> [3072][1024]
__global__ void transpose_w3(const float* __restrict__ w0, const float* __restrict__ w1,
                             const float* __restrict__ w2, bf16_t* __restrict__ oT) {
  const float* w = blockIdx.z == 0 ? w0 : (blockIdx.z == 1 ? w1 : w2);
  bf16_t* o = oT + (size_t)blockIdx.z * D_ * D_;
  __shared__ float t[32][33];
  const int tx = threadIdx.x, ty = threadIdx.y;
  const int x  = blockIdx.x * 32 + tx;
  const int y0 = blockIdx.y * 32;
  #pragma unroll
  for (int j = 0; j < 4; ++j)
    t[ty + j * 8][tx] = w[(size_t)(y0 + ty + j * 8) * D_ + x];
  __syncthreads();
  const int x2 = y0 + tx;
  const int y2 = blockIdx.x * 32;
  #pragma unroll
  for (int j = 0; j < 4; ++j)
    o[(size_t)(y2 + ty + j * 8) * D_ + x2] = (bf16_t)t[tx][ty + j * 8];
}

extern "C" void kernel_launch(void* const* d_in, const int* in_sizes, int n_in,
                              void* d_out, int out_size, void* d_ws, size_t ws_size,
                              hipStream_t stream) {
  const float* x  = (const float*)d_in[0];
  // d_in[1] = causal mask, structurally known -> ignored
  const float* wq = (const float*)d_in[2];
  const float* bq = (const float*)d_in[3];
  const float* wk = (const float*)d_in[4];
  const float* bk = (const float*)d_in[5];
  const float* wv = (const float*)d_in[6];
  const float* bv = (const float*)d_in[7];
  float* out = (float*)d_out;

  // workspace layout (bf16 elems), ~118 MB total
  bf16_t* xb   = (bf16_t*)d_ws;                    // [8192][1024]    16 MB
  bf16_t* wT   = xb  + (size_t)M_ * D_;            // [3072][1024]     6 MB (W^T, q|k|v)
  bf16_t* qkv  = wT  + (size_t)N3_ * D_;           // [8192][3072]    48 MB (q pre-scaled; V cols unused)
  bf16_t* vbT  = qkv + (size_t)M_ * N3_;           // [1024][8192]    16 MB (V^T, written by proj)
  bf16_t* Sb   = vbT + (size_t)M_ * D_;            // [4][2048][2048] 32 MB bf16
  bf16_t* Pfull = qkv;                             // [4][2048][2048] 32 MB (aliases dead qkv)

  const size_t SMEM = 81920;   // 80 KiB: A 3-buf (48K) + B 2-buf (32K) -> 2 blocks/CU

  cvt_f32_bf16<<<1024, 256, 0, stream>>>(x, xb, M_ * D_ / 4);
  transpose_w3<<<dim3(32, 32, 3), dim3(32, 8), 0, stream>>>(wq, wk, wv, wT);

  // fused projection GEMM: q|k cols -> qkv; V cols -> vbT transposed (fused V^T)
  gemm4<true, false, false, true><<<dim3(N3_ / 128, M_ / 128), 256, SMEM, stream>>>(
      xb, D_, 0, wT, D_, 0, qkv, N3_, 0, vbT, bq, bk, bv, D_);

  // QK^T for all batches (Q = cols [0,1024), K = cols [1024,2048)), bf16 logits
  gemm4<true, true, false, false><<<dim3(L_ / 128, L_ / 128, B_), 256, SMEM, stream>>>(
      qkv, N3_, (long)L_ * N3_, qkv + D_, N3_, (long)L_ * N3_, Sb, L_, (long)L_ * L_,
      nullptr, nullptr, nullptr, nullptr, D_);

  // softmax for all batches (writes Pfull over dead qkv)
  softmax_causal<<<dim3(L_, B_), 256, 0, stream>>>(Sb, Pfull);

  // PV for all batches (512 blocks = exactly 2/CU, single scheduling round)
  gemm4<false, false, true, false><<<dim3(D_ / 128, L_ / 128, B_), 256, SMEM, stream>>>(
      Pfull, L_, (long)L_ * L_, vbT, M_, (long)L_, out, D_, (long)L_ * D_,
      nullptr, nullptr, nullptr, nullptr, L_);
}